// Round 7
// baseline (901.292 us; speedup 1.0000x reference)
//
#include <hip/hip_runtime.h>
#include <cstddef>

#define THRESH 1e-6f
#define SPIN_LIMIT (1 << 20)

__device__ __forceinline__ float thrf(float x) { return x > THRESH ? x : 0.0f; }
__device__ __forceinline__ float sigm(float x) { return 1.0f / (1.0f + expf(-x)); }
__device__ __forceinline__ void fma4(float4& c, float a, float4 b) {
    c.x += a * b.x; c.y += a * b.y; c.z += a * b.z; c.w += a * b.w;
}
__device__ __forceinline__ void macc4(float4& a, float4 w, float4 h) {
    a.x += w.x * h.x; a.y += w.y * h.y; a.z += w.z * h.z; a.w += w.w * h.w;
}
__device__ __forceinline__ float hsum4(float4 a) { return a.x + a.y + a.z + a.w; }

// ---------------------------------------------------------------------------
// K1: fused gather+MLP GEMM (unchanged — proven).
// ---------------------------------------------------------------------------
__global__ __launch_bounds__(256) void k_embed_gemm(const int* __restrict__ tok,
                                                    const float* __restrict__ W1,
                                                    const float* __restrict__ b1,
                                                    const float* __restrict__ W2,
                                                    const float* __restrict__ b2,
                                                    float* __restrict__ emb) {
    constexpr int BM = 64, BN = 64, BK = 32, K = 512, N = 256;
    __shared__ float As[BK][BM + 1];
    __shared__ float Bs[BK][BN];

    const int tid = threadIdx.x;
    const int bm = blockIdx.x * BM;
    const int bn = blockIdx.y * BN;
    const int tn = (tid & 15) * 4;
    const int tm = (tid >> 4) * 4;

    float acc[4][4] = {};

    for (int k0 = 0; k0 < K; k0 += BK) {
        for (int i = tid; i < BM * BK / 4; i += 256) {
            int c4 = (i & (BK / 4 - 1)) * 4;
            int r  = i / (BK / 4);
            int tv = tok[bm + r];
            float4 v  = *(const float4*)(W1 + (size_t)tv * K + k0 + c4);
            float4 bb = *(const float4*)(b1 + k0 + c4);
            As[c4 + 0][r] = thrf(v.x + bb.x);
            As[c4 + 1][r] = thrf(v.y + bb.y);
            As[c4 + 2][r] = thrf(v.z + bb.z);
            As[c4 + 3][r] = thrf(v.w + bb.w);
        }
        for (int i = tid; i < BK * BN / 4; i += 256) {
            int n4 = (i & 15) * 4;
            int kk = i >> 4;
            *(float4*)&Bs[kk][n4] = *(const float4*)(W2 + (size_t)(k0 + kk) * N + bn + n4);
        }
        __syncthreads();

        for (int k = 0; k < BK; ++k) {
            float a0 = As[k][tm + 0], a1 = As[k][tm + 1];
            float a2 = As[k][tm + 2], a3 = As[k][tm + 3];
            float b0 = Bs[k][tn + 0], b1v = Bs[k][tn + 1];
            float b2v = Bs[k][tn + 2], b3v = Bs[k][tn + 3];
            acc[0][0] += a0 * b0;  acc[0][1] += a0 * b1v;
            acc[0][2] += a0 * b2v; acc[0][3] += a0 * b3v;
            acc[1][0] += a1 * b0;  acc[1][1] += a1 * b1v;
            acc[1][2] += a1 * b2v; acc[1][3] += a1 * b3v;
            acc[2][0] += a2 * b0;  acc[2][1] += a2 * b1v;
            acc[2][2] += a2 * b2v; acc[2][3] += a2 * b3v;
            acc[3][0] += a3 * b0;  acc[3][1] += a3 * b1v;
            acc[3][2] += a3 * b2v; acc[3][3] += a3 * b3v;
        }
        __syncthreads();
    }

    const float4 bv = *(const float4*)(b2 + bn + tn);
    for (int i = 0; i < 4; ++i) {
        int m = bm + tm + i;
        float4 o;
        o.x = thrf(acc[i][0] + bv.x);
        o.y = thrf(acc[i][1] + bv.y);
        o.z = thrf(acc[i][2] + bv.z);
        o.w = thrf(acc[i][3] + bv.w);
        *(float4*)(emb + (size_t)m * N + bn + tn) = o;
    }
}

// ---------------------------------------------------------------------------
// K2: x_proj = emb @ W_ih^T + b_ih  (unchanged — proven).
// ---------------------------------------------------------------------------
__global__ __launch_bounds__(256) void k_xproj(const float* __restrict__ emb,   // (4096,256)
                                               const float* __restrict__ W_ih,  // (1536,256)
                                               const float* __restrict__ b_ih,  // (1536)
                                               float* __restrict__ xp) {        // (4096,1536)
    constexpr int BM = 128, BJ = 64, BK = 32, K = 256, J = 1536;
    __shared__ __align__(16) float As[BK][BM + 4];
    __shared__ __align__(16) float Bs[BK][BJ + 4];
    const int tid = threadIdx.x;
    const int bm = blockIdx.x * BM;
    const int bj = blockIdx.y * BJ;
    const int tj = (tid & 15) * 4;
    const int tm = (tid >> 4) * 8;

    float4 acc[8];
#pragma unroll
    for (int i = 0; i < 8; ++i) acc[i] = make_float4(0.f, 0.f, 0.f, 0.f);

    for (int k0 = 0; k0 < K; k0 += BK) {
#pragma unroll
        for (int p = 0; p < 4; ++p) {
            int i = tid + p * 256;
            int c4 = (i & 7) * 4, r = i >> 3;
            float4 v = *(const float4*)(emb + (size_t)(bm + r) * K + k0 + c4);
            As[c4 + 0][r] = v.x; As[c4 + 1][r] = v.y;
            As[c4 + 2][r] = v.z; As[c4 + 3][r] = v.w;
        }
#pragma unroll
        for (int p = 0; p < 2; ++p) {
            int i = tid + p * 256;
            int c4 = (i & 7) * 4, r = i >> 3;
            float4 v = *(const float4*)(W_ih + (size_t)(bj + r) * K + k0 + c4);
            Bs[c4 + 0][r] = v.x; Bs[c4 + 1][r] = v.y;
            Bs[c4 + 2][r] = v.z; Bs[c4 + 3][r] = v.w;
        }
        __syncthreads();

#pragma unroll 8
        for (int k = 0; k < BK; ++k) {
            float4 b4 = *(const float4*)&Bs[k][tj];
            float4 a0 = *(const float4*)&As[k][tm];
            float4 a1 = *(const float4*)&As[k][tm + 4];
            fma4(acc[0], a0.x, b4); fma4(acc[1], a0.y, b4);
            fma4(acc[2], a0.z, b4); fma4(acc[3], a0.w, b4);
            fma4(acc[4], a1.x, b4); fma4(acc[5], a1.y, b4);
            fma4(acc[6], a1.z, b4); fma4(acc[7], a1.w, b4);
        }
        __syncthreads();
    }

    const float4 bb = *(const float4*)(b_ih + bj + tj);
#pragma unroll
    for (int i = 0; i < 8; ++i) {
        float4 o = make_float4(acc[i].x + bb.x, acc[i].y + bb.y,
                               acc[i].z + bb.z, acc[i].w + bb.w);
        *(float4*)(xp + (size_t)(bm + tm + i) * J + bj + tj) = o;
    }
}

// ---------------------------------------------------------------------------
// K3: GRU scan — LDS-RESIDENT weights + LL exchange + in-wave reduce.
// 256 blocks x 256 threads = 8 groups (bid&7) x 32 members (bid>>3).
// Member owns j-slice [m*16, m*16+16); group owns batches [g*4, g*4+4).
// Thread layout (lane = tid&63, wave = tid>>6, 4 waves/block):
//   kc   = lane&15  -> contiguous k-chunk [32*kc, 32*kc+32)
//   jlow = lane>>4  -> j = m*16 + wave*4 + jlow
//
// WEIGHTS IN LDS (the R5/R6 lesson): the compiler twice refused to hold
// 96 f32/thread of W_hh in VGPRs (VGPR_Count 100, weights rematerialized
// from L2 every step: FETCH +8MB, ~1us/step).  LDS residency is structural
// — 48 rows x 512 f32 = 96KB + hl 18KB = 117KB < 160KB/CU, 1 block/CU.
// Row-internal XOR swizzle: logical f4-chunk i of lane kc stored at slot
// kc*8 + (i^(kc&7)).  At fixed i the 64 lanes spread uniformly over all 32
// banks (balanced 8-way = wave64-b128 minimum; unswizzled would be 4 banks
// = 8x serialization).  h layout (kc*36 skew) identical to R6: 0 conflicts.
//
// All 16 kc of a j in ONE wave -> k-reduce = 4 shfl_xor; lanes kc<4
// finalize batch kc and publish immediately after their wave's shuffles.
// LL safety: publishing tag t+1 requires passing the step-t barrier, which
// requires all producers' tag-t, which requires every member passed barrier
// t-1, i.e. fully consumed tag t-1 -> the overwritten parity slot is dead.
// ONE __syncthreads per step.
// ---------------------------------------------------------------------------
__global__ __launch_bounds__(256) void k_scan(const float* __restrict__ xp,    // (4096,1536)
                                              const float* __restrict__ W_hh,  // (1536,512)
                                              const float* __restrict__ b_hh,  // (1536)
                                              unsigned long long* __restrict__ hx, // (2,32,512) u64
                                              float* __restrict__ h_out) {     // (32,512)
    constexpr int CH = 576;                         // 512 + 16*4 skew pad
    __shared__ __align__(16) float Wl[3 * 16 * 512];   // 96 KB swizzled weights
    __shared__ __align__(16) float hl[2][4 * CH];      // 18 KB h double-buffer

    const int tid  = threadIdx.x;
    const int g    = blockIdx.x & 7;
    const int m    = blockIdx.x >> 3;              // 0..31
    const int lane = tid & 63;
    const int wave = tid >> 6;                     // 0..3
    const int kc   = lane & 15;
    const int jlow = lane >> 4;                    // 0..3
    const int wjj  = wave * 4 + jlow;              // j-local 0..15
    const int jglob = m * 16 + wjj;
    const int hoff  = kc * 36;                     // skewed h chunk base
    const int kx    = kc & 7;                      // weight swizzle key

    // ---- stage this member's 48 W_hh rows into LDS (once, swizzled) ----
    // logical (gg, jj, f4) with f4 = kc_*8 + ii  ->  slot kc_*8 + (ii^kc_&7)
    for (int idx = tid; idx < 3 * 16 * 128; idx += 256) {
        const int gg  = idx >> 11;                 // /2048
        const int rem = idx & 2047;
        const int jj  = rem >> 7;                  // /128
        const int f4  = rem & 127;
        const int kcs = f4 >> 3, ii = f4 & 7;
        const int f4s = (kcs << 3) | (ii ^ (kcs & 7));
        const float4 v = *(const float4*)(W_hh + (size_t)(gg * 512 + m * 16 + jj) * 512 + f4 * 4);
        *(float4*)&Wl[(((gg << 4) + jj) << 9) + f4s * 4] = v;
    }

    // per-lane weight row bases (chunk base kc*8 f4s = kc*32 floats)
    const float* w0 = &Wl[(( 0 + wjj) << 9) + kc * 32];
    const float* w1 = &Wl[((16 + wjj) << 9) + kc * 32];
    const float* w2 = &Wl[((32 + wjj) << 9) + kc * 32];

    // finalizer lanes (kc<4): handle (j = jglob, batch = g*4+kc)
    const int bg = g * 4 + kc;
    float bhr = 0.f, bhz = 0.f, bhn = 0.f, hprev = 0.f;
    if (kc < 4) {
        bhr = b_hh[jglob];
        bhz = b_hh[512 + jglob];
        bhn = b_hh[1024 + jglob];
    }

    // h(0) = 0 (buffer 0); ordered before the t=0 dot by the in-loop barrier
    for (int i = tid; i < 4 * CH; i += 256) hl[0][i] = 0.f;

    // staging assignment: 8 consecutive LL words (one j-run inside one batch)
    const int sflat = tid * 8;
    const int sb = sflat >> 9, sk = sflat & 511;
    const int sdst = sb * CH + sk + ((sk >> 5) << 2);

    for (int t = 0; t < 128; ++t) {
        // x(t) issued first — latency hides under the LL poll
        float xr = 0.f, xz = 0.f, xn = 0.f;
        if (kc < 4) {
            const float* xrow = xp + (size_t)(t * 32 + bg) * 1536;
            xr = xrow[jglob];
            xz = xrow[512 + jglob];
            xn = xrow[1024 + jglob];
        }

        if (t > 0) {
            const unsigned tag = (unsigned)t;
            unsigned long long* base = hx + (size_t)(t & 1) * 16384
                                          + (size_t)(g * 4) * 512 + sflat;
            unsigned long long v[8];
#pragma unroll
            for (int p = 0; p < 8; ++p)
                v[p] = __hip_atomic_load(base + p, __ATOMIC_RELAXED, __HIP_MEMORY_SCOPE_AGENT);
            int spins = 0;
            for (;;) {
                bool all = true;
#pragma unroll
                for (int p = 0; p < 8; ++p) {
                    if ((unsigned)(v[p] >> 32) != tag) {
                        all = false;
                        v[p] = __hip_atomic_load(base + p, __ATOMIC_RELAXED, __HIP_MEMORY_SCOPE_AGENT);
                    }
                }
                if (all || ++spins > SPIN_LIMIT) break;
                __builtin_amdgcn_s_sleep(1);
            }
            union { unsigned u; float f; } c0, c1, c2, c3, c4, c5, c6, c7;
            c0.u = (unsigned)v[0]; c1.u = (unsigned)v[1];
            c2.u = (unsigned)v[2]; c3.u = (unsigned)v[3];
            c4.u = (unsigned)v[4]; c5.u = (unsigned)v[5];
            c6.u = (unsigned)v[6]; c7.u = (unsigned)v[7];
            *(float4*)&hl[t & 1][sdst]     = make_float4(c0.f, c1.f, c2.f, c3.f);
            *(float4*)&hl[t & 1][sdst + 4] = make_float4(c4.f, c5.f, c6.f, c7.f);
        }
        __syncthreads();   // the single per-step barrier (also orders W/h init)

        // ---- dot: 3 gates x 4 batches over k in [32kc, 32kc+32) ----
        const float* hb = hl[t & 1];
        float4 ar[4], az[4], an[4];
#pragma unroll
        for (int b = 0; b < 4; ++b) {
            ar[b] = make_float4(0.f, 0.f, 0.f, 0.f);
            az[b] = ar[b]; an[b] = ar[b];
        }
#pragma unroll
        for (int i = 0; i < 8; ++i) {
            const int io = (i ^ kx) << 2;          // swizzled slot of logical i
            const float4 wrv = *(const float4*)(w0 + io);
            const float4 wzv = *(const float4*)(w1 + io);
            const float4 wnv = *(const float4*)(w2 + io);
#pragma unroll
            for (int b = 0; b < 4; ++b) {
                const float4 h4 = *(const float4*)(hb + b * CH + hoff + i * 4);
                macc4(ar[b], wrv, h4);
                macc4(az[b], wzv, h4);
                macc4(an[b], wnv, h4);
            }
        }
        float p[3][4];
#pragma unroll
        for (int b = 0; b < 4; ++b) {
            p[0][b] = hsum4(ar[b]); p[1][b] = hsum4(az[b]); p[2][b] = hsum4(an[b]);
        }

        // ---- in-wave reduce over kc (lane bits 0..3) ----
#pragma unroll
        for (int gg = 0; gg < 3; ++gg)
#pragma unroll
            for (int b = 0; b < 4; ++b) {
                float v = p[gg][b];
                v += __shfl_xor(v, 1);
                v += __shfl_xor(v, 2);
                v += __shfl_xor(v, 4);
                v += __shfl_xor(v, 8);
                p[gg][b] = v;
            }

        // ---- finalize + per-wave publish: lane kc handles batch kc ----
        if (kc < 4) {
            float sr, sz, sn;
            if      (kc == 0) { sr = p[0][0]; sz = p[1][0]; sn = p[2][0]; }
            else if (kc == 1) { sr = p[0][1]; sz = p[1][1]; sn = p[2][1]; }
            else if (kc == 2) { sr = p[0][2]; sz = p[1][2]; sn = p[2][2]; }
            else              { sr = p[0][3]; sz = p[1][3]; sn = p[2][3]; }
            float r  = sigm(xr + sr + bhr);
            float z  = sigm(xz + sz + bhz);
            float n  = tanhf(xn + r * (sn + bhn));
            float hn = (1.0f - z) * n + z * hprev;
            hprev = hn;
            if (t < 127) {
                union { float f; unsigned u; } cv; cv.f = hn;
                __hip_atomic_store(hx + (size_t)((t + 1) & 1) * 16384
                                      + (size_t)bg * 512 + jglob,
                                   ((unsigned long long)(unsigned)(t + 1) << 32) | cv.u,
                                   __ATOMIC_RELAXED, __HIP_MEMORY_SCOPE_AGENT);
            } else {
                h_out[(size_t)bg * 512 + jglob] = hn;
            }
        }
        // no bottom barrier: next staging writes the OTHER hl buffer
    }
}

// ---------------------------------------------------------------------------
// K4: head (unchanged).
// ---------------------------------------------------------------------------
__global__ __launch_bounds__(256) void k_head(const float* __restrict__ h,
                                              const float* __restrict__ W3,
                                              const float* __restrict__ b3,
                                              float* __restrict__ out) {
    const int b = blockIdx.x;
    const int o = threadIdx.x;
    const float* hrow = h + (size_t)b * 512;
    float acc = b3[o];
#pragma unroll 8
    for (int k = 0; k < 512; ++k)
        acc += hrow[k] * W3[(size_t)k * 256 + o];
    out[(size_t)b * 256 + o] = acc;
}

// ---------------------------------------------------------------------------
extern "C" void kernel_launch(void* const* d_in, const int* in_sizes, int n_in,
                              void* d_out, int out_size, void* d_ws, size_t ws_size,
                              hipStream_t stream) {
    // 0:input 1:W1 2:b1 3:W2 4:b2 5:W_ih 6:W_hh 7:b_ih 8:b_hh 9:W3 10:b3
    const int*   tok  = (const int*)d_in[0];
    const float* W1   = (const float*)d_in[1];
    const float* b1   = (const float*)d_in[2];
    const float* W2   = (const float*)d_in[3];
    const float* b2   = (const float*)d_in[4];
    const float* W_ih = (const float*)d_in[5];
    const float* W_hh = (const float*)d_in[6];
    const float* b_ih = (const float*)d_in[7];
    const float* b_hh = (const float*)d_in[8];
    const float* W3   = (const float*)d_in[9];
    const float* b3   = (const float*)d_in[10];
    float* out = (float*)d_out;
    (void)ws_size;

    // workspace (floats):
    //   emb : 1,048,576      (4096x256)
    //   xp  : 6,291,456      (4096x1536)
    //   hx  : 65,536 f-equiv (2x32x512 u64 LL slots; exact-tag poll makes
    //                         0xAA poison harmless — no memset needed)
    //   hfin: 16,384         (32x512)
    float* ws   = (float*)d_ws;
    float* emb  = ws;
    float* xp   = ws + 1048576;
    unsigned long long* hx = (unsigned long long*)(ws + 7340032);  // 8B-aligned
    float* hfin = ws + 7340032 + 65536;

    {   // fused embedding MLP
        dim3 grd(4096 / 64, 256 / 64);
        k_embed_gemm<<<grd, 256, 0, stream>>>(tok, W1, b1, W2, b2, emb);
    }
    {   // input projections for all timesteps (b_ih folded in)
        dim3 grd(4096 / 128, 1536 / 64);
        k_xproj<<<grd, 256, 0, stream>>>(emb, W_ih, b_ih, xp);
    }
    // LL-exchange GRU scan: 8 groups x 32 members, LDS weights, in-wave reduce
    k_scan<<<256, 256, 0, stream>>>(xp, W_hh, b_hh, hx, hfin);

    // head on final hidden state
    k_head<<<32, 256, 0, stream>>>(hfin, W3, b3, out);
}